// Round 19
// baseline (74.520 us; speedup 1.0000x reference)
//
#include <hip/hip_runtime.h>
#include <hip/hip_fp16.h>
#include <math.h>
#include <string.h>

typedef __attribute__((ext_vector_type(8))) short short8;
typedef __attribute__((ext_vector_type(8))) _Float16 f16x8;
typedef __attribute__((ext_vector_type(4))) _Float16 h4;
typedef __attribute__((ext_vector_type(2))) _Float16 h2;
typedef __attribute__((ext_vector_type(4))) float f32x4;

#define NB 16
#define NM 16
#define NN 32
#define NT 80
#define TC 20   // timesteps per partial block (16-row MFMA tile + 4-row tail tile)
#define NP 4    // partial blocks per (b,m): grid 1024 = exactly 4/CU, no tail round
#define CH 4    // agents per hidden chunk
#define NCH 8   // chunks (NN/CH)

// ---- d_ws float-slot layout ----
#define WS_WTS 0                 // 8 floats: softplus weights
#define WS_BF 16                 // 8192 float-slots: f16 frag table enc_w2 (32 KB)
#define WS_BB 8208               // 16384 float-slots: baseB[b][n][32 h2] (64 KB)
#define WS_BASE 24592            // partials, WS_BM_STRIDE per bm
#define WS_BM_STRIDE 1088        // NP*256 feat partials + 64 scalars
#define WS_SC_OFF 1024           // within-bm offset of scalar partials

__device__ __forceinline__ short f2h(float f) {
  _Float16 h = (_Float16)f;
  short s; memcpy(&s, &h, 2); return s;
}
__device__ __forceinline__ unsigned h2bits(h2 h) {
  unsigned u; memcpy(&u, &h, 4); return u;
}
__device__ __forceinline__ h2 bits2h(unsigned u) {
  h2 h; memcpy(&h, &u, 4); return h;
}

// ---------------- kernel 0: prep — f16 weight tables + weights head ----------
// blocks 0..15: baseB for b = blk. blocks 16..23: Bf table, 4 slots each.
// block 24: weights head (256-thread split).
__global__ void prep_kernel(const float* __restrict__ agents_states,
                            const float* __restrict__ enc_w1,
                            const float* __restrict__ enc_b1,
                            const float* __restrict__ enc_w2,
                            const float* __restrict__ wd_w1,
                            const float* __restrict__ wd_b1,
                            const float* __restrict__ wd_w2,
                            const float* __restrict__ wd_b2,
                            float* __restrict__ ws,
                            float* __restrict__ out) {
  const int blk = blockIdx.x;
  const int tid = threadIdx.x;
  if (blk < NB) {
    // baseB[b][n][j] = enc_b1[j] + mask_n * (states[6:11] @ enc_w1[5:10,j]) -> h2
    __shared__ float smask[NN];
    if (tid < NN) {
      const float* st = agents_states + ((size_t)blk * NN + tid) * 11;
      float s = 0.f;
      for (int i = 0; i < 11; ++i) s += st[i];
      smask[tid] = (s != 0.f) ? 1.f : 0.f;
    }
    __syncthreads();
    h2* bb = reinterpret_cast<h2*>(ws + WS_BB) + blk * (NN * 32);
    for (int e = tid; e < NN * 32; e += 256) {   // e = n*32 + jpair
      int n = e >> 5, jp = e & 31;
      const float* st = agents_states + ((size_t)blk * NN + n) * 11 + 6;
      float v[2];
#pragma unroll
      for (int hh = 0; hh < 2; ++hh) {
        int j = jp * 2 + hh;
        float acc = st[0] * enc_w1[5 * 64 + j] + st[1] * enc_w1[6 * 64 + j] +
                    st[2] * enc_w1[7 * 64 + j] + st[3] * enc_w1[8 * 64 + j] +
                    st[4] * enc_w1[9 * 64 + j];
        v[hh] = smask[n] * acc + enc_b1[j];
      }
      h2 r; r[0] = (_Float16)v[0]; r[1] = (_Float16)v[1];
      bb[e] = r;
    }
  } else if (blk < NB + 8) {
    // Bf fragment table: 4 slots per block, 1 slot per wave group
    const int g = tid >> 6;
    const int lane = tid & 63;
    const int s = (blk - NB) * 4 + g;
    const int wv = s >> 3, jb = (s >> 1) & 3, kt = s & 1;
    const int col = wv * 64 + jb * 16 + (lane & 15);
    const int krow = (lane >> 4) * 8;
    short8 v;
#pragma unroll
    for (int j = 0; j < 8; ++j)
      v[j] = f2h(enc_w2[(kt * 32 + krow + j) * 256 + col]);
    reinterpret_cast<short8*>(ws + WS_BF)[s * 64 + lane] = v;
  } else {
    // weights head (enc_in = ones), 256 threads: 4 groups x 64 rows of wd_w1
    __shared__ float s_part[4][64];
    __shared__ float sh[64];
    const int g = tid >> 6, j = tid & 63;
    {
      float a = 0.f;
#pragma unroll 8
      for (int i = 0; i < 64; ++i)
        a += wd_w1[(g * 64 + i) * 64 + j];
      s_part[g][j] = a;
    }
    __syncthreads();
    if (tid < 64) {
      float acc = wd_b1[tid] + ((s_part[0][tid] + s_part[1][tid]) +
                                (s_part[2][tid] + s_part[3][tid]));
      sh[tid] = acc > 0.f ? acc : expm1f(acc);  // elu
    }
    __syncthreads();
    if (tid < 8) {
      float acc = wd_b2[tid];
      for (int k = 0; k < 64; ++k) acc += sh[k] * wd_w2[k * 8 + tid];
      float sp = log1pf(__expf(acc));  // softplus
      ws[WS_WTS + tid] = sp;
      for (int b = 0; b < NB; ++b) out[NB * NM + b * 8 + tid] = sp;
    }
  }
}

// ---------------- kernel 1: t-on-rows partial kernel, TC=20 -----------------
// 16-row main MFMA tile (t0..t0+15) + 4-row tail tile (t0+16..t0+19 in C rows
// 0-3; tail contributions summed only from kg==0 lanes, so garbage rows in
// kg>=1 never enter the result). GEMM1 mapping: jq=tid>>4, tt=tid&15 (spreads
// the tt<4 double-row work evenly across all 4 waves).
__global__ __launch_bounds__(256, 4) void score_partial(
    const float* __restrict__ ego_traj,      // [B][M][T][6]
    const float* __restrict__ agents_traj,   // [B][M][N][T][3]
    const float* __restrict__ agents_states, // [B][N][11]
    const float* __restrict__ enc_w1,        // [10][64]
    float* __restrict__ ws)
{
  __shared__ h4 s_r01[NN][TC];                         // (f0,f0,f1,f1) per (n,t)
  __shared__ h4 s_r23[NN][TC];                         // (f2,f2,f3,f3)
  __shared__ h2 s_r4[NN][TC];                          // (f4,f4)
  __shared__ uint2 s_bb[NN][16];                       // baseB j-quads, 4 KB
  __shared__ __align__(16) char s_hid[2][CH][TC * 128];// 20 KB dbuf f16 tile
  __shared__ float s_ego[TC][5];
  __shared__ float s_acc[TC + 2];
  __shared__ float s_spd[TC], s_lat[TC], s_egos[TC];
  __shared__ float s_mask[NN];
  __shared__ float s_cw[4];

  const int p = blockIdx.x;
  const int bm = blockIdx.y;
  const int t0 = p * TC;
  const int b = bm >> 4;
  const int tid = threadIdx.x;
  const int lane = tid & 63;
  const int wv = tid >> 6;

  float* ws_bm = ws + WS_BASE + (size_t)bm * WS_BM_STRIDE;

  // ---- phase A: ego staging + agent mask + baseB LDS stage ----
  if (tid < TC) {
    int i = tid;
    const float* e = ego_traj + ((size_t)bm * NT + (t0 + i)) * 6;
    float ex = e[0], ey = e[1], eh = e[2], spd = e[3], acc = e[4], cur = e[5];
    s_ego[i][0] = ex; s_ego[i][1] = ey; s_ego[i][2] = eh;
    s_ego[i][3] = spd * __cosf(eh);
    s_ego[i][4] = spd * __sinf(eh);
    s_spd[i] = spd;
    s_acc[i + 1] = acc;
    s_lat[i] = fabsf(spd * spd * cur);
    s_egos[i] = ex + ey + eh + spd + acc + cur;
  } else if (tid == TC) {
    int tp = (p == 0) ? 0 : (t0 - 1);
    s_acc[0] = ego_traj[((size_t)bm * NT + tp) * 6 + 4];
  } else if (tid >= 64 && tid < 64 + NN) {
    int n = tid - 64;
    const float* st = agents_states + ((size_t)b * NN + n) * 11;
    float s = 0.f;
    for (int i = 0; i < 11; ++i) s += st[i];
    s_mask[n] = (s != 0.f) ? 1.f : 0.f;
  }
  {
    const uint2* bbt = reinterpret_cast<const uint2*>(ws + WS_BB) + b * 512;
#pragma unroll
    for (int k = 0; k < 2; ++k) {
      int e = tid + k * 256;                 // 512 = NN*16 j-quads
      s_bb[e >> 4][e & 15] = bbt[e];
    }
  }

  const int jq = tid >> 4;        // j-quad within 64-col wave slice (0..15)
  const int tt = tid & 15;        // GEMM1 main row (local t 0..15)
  const int j0 = (jq & 3) * 4 + wv * 0;  // NOTE: jq spans 0..15 across block;
  // each wave holds jq = wv*4 .. wv*4+3, i.e. 4 j-quads x 16 rows.
  // w1h/baseB use the GLOBAL j-quad (jq&15) -> j0 = (jq&15)*4? jq is 0..15
  // already global. j0 = jq*4 indexes enc_w1 columns 0..63. Correct:
  const int j0g = jq * 4;

  f16x8 Bf[4][2];
  {
    const f16x8* bft = reinterpret_cast<const f16x8*>(ws + WS_BF);
#pragma unroll
    for (int jb = 0; jb < 4; ++jb)
#pragma unroll
      for (int kt = 0; kt < 2; ++kt)
        Bf[jb][kt] = bft[((wv * 4 + jb) * 2 + kt) * 64 + lane];
  }

  h2 w1h[5][2];
#pragma unroll
  for (int f = 0; f < 5; ++f)
#pragma unroll
    for (int jp = 0; jp < 2; ++jp) {
      h2 r;
      r[0] = (_Float16)enc_w1[f * 64 + j0g + jp * 2];
      r[1] = (_Float16)enc_w1[f * 64 + j0g + jp * 2 + 1];
      w1h[f][jp] = r;
    }
  __syncthreads();  // barrier 1: s_ego/s_mask ready

  // ---- phase B: rel features for 32n x 20t (640 pairs) + coll ----
  {
    float collacc = 0.f;
    const float* atraj = agents_traj + (size_t)bm * (NN * NT * 3);
#pragma unroll
    for (int k = 0; k < 3; ++k) {
      int pp = tid + k * 256;
      if (pp < NN * TC) {
        int n = pp / TC;
        int i = pp - n * TC;
        int tg = t0 + i;
        const float* bp = atraj + n * (NT * 3) + tg * 3;
        float ax = bp[0], ay = bp[1], ah = bp[2];
        float avx, avy;
        if (tg == 0) { avx = (bp[3] - ax) * 10.f; avy = (bp[4] - ay) * 10.f; }
        else         { avx = (ax - bp[-3]) * 10.f; avy = (ay - bp[-2]) * 10.f; }
        float ex = s_ego[i][0], ey = s_ego[i][1], eh = s_ego[i][2];
        float evx = s_ego[i][3], evy = s_ego[i][4];
        float m = s_mask[n];
        float ryr = ah - eh;
        float w = ryr - 6.283185307179586f * rintf(ryr * 0.15915494309189535f);
        float cy = __cosf(ryr), sy = __sinf(ryr);
        float dx = ax - ex, dy = ay - ey;
        float r0 = dx * cy * m, r1 = dy * sy * m, r2 = w * m;
        float r3 = (avx - evx) * cy * m, r4 = (avy - evy) * sy * m;
        h4 v01, v23; h2 v4;
        v01[0] = v01[1] = (_Float16)r0; v01[2] = v01[3] = (_Float16)r1;
        v23[0] = v23[1] = (_Float16)r2; v23[2] = v23[3] = (_Float16)r3;
        v4[0] = v4[1] = (_Float16)r4;
        s_r01[n][i] = v01;
        s_r23[n][i] = v23;
        s_r4[n][i] = v4;
        collacc += __expf(-0.2f * (dx * dx + dy * dy)) * m;
      }
    }
#pragma unroll
    for (int off = 1; off < 64; off <<= 1) collacc += __shfl_xor(collacc, off);
    if (lane == 0) s_cw[wv] = collacc;
  }

  // hard-feature partial sums on high tids
  if (tid >= 251) {
    int which = tid - 251;
    float s = 0.f;
    if (which == 0)      { for (int i = 0; i < TC; ++i) s += s_spd[i]; }
    else if (which == 1) { for (int i = 0; i < TC; ++i) s += fabsf(s_acc[i + 1]); }
    else if (which == 2) {
      for (int i = 0; i < TC; ++i) {
        int ia = (p == 0 && i == 0) ? 2 : (i + 1);
        s += fabsf((s_acc[ia] - s_acc[ia - 1]) * 10.f);
      }
    }
    else if (which == 3) { for (int i = 0; i < TC; ++i) s += s_lat[i]; }
    else                 { for (int i = 0; i < TC; ++i) s += s_egos[i]; }
    ws_bm[WS_SC_OFF + p * 8 + which] = s;
  }

  // A-read offsets: main tile rows = lane&15; tail tile rows = 16 + (tl&3)
  const int tl = lane & 15, kg = lane >> 4;
  const int swr = (tl & 7) << 4;
  const int aoff0 = tl * 128 + ((kg * 16) ^ swr);
  const int aoff1 = tl * 128 + ((64 + kg * 16) ^ swr);
  const int tl4 = tl & 3;
  const int swr2 = tl4 << 4;                      // (16+tl4)&7 == tl4
  const int aoff2_0 = (16 + tl4) * 128 + ((kg * 16) ^ swr2);
  const int aoff2_1 = (16 + tl4) * 128 + ((64 + kg * 16) ^ swr2);
  const int wbyte  = tt * 128 + ((jq * 8 & 127) ^ ((tt & 7) << 4));
  const int wbyte2 = (16 + tt) * 128 + ((jq * 8 & 127) ^ ((tt & 7) << 4));
  // jq*8 ranges 0..120 within the 128B row; (&127) is a no-op kept for clarity.

  h2 z2; z2[0] = z2[1] = (_Float16)0.f;

  auto gemm1_row = [&](int n, int i, uint2 bb) -> uint2 {
    h4 r01 = s_r01[n][i];
    h4 r23 = s_r23[n][i];
    h2 r4 = s_r4[n][i];
    h2 a0 = __builtin_shufflevector(r01, r01, 0, 1);
    h2 a1 = __builtin_shufflevector(r01, r01, 2, 3);
    h2 a2 = __builtin_shufflevector(r23, r23, 0, 1);
    h2 a3 = __builtin_shufflevector(r23, r23, 2, 3);
    uint2 u;
#pragma unroll
    for (int jp = 0; jp < 2; ++jp) {
      h2 ha = bits2h(jp ? bb.y : bb.x);
      ha = a0 * w1h[0][jp] + ha;
      ha = a1 * w1h[1][jp] + ha;
      ha = a2 * w1h[2][jp] + ha;
      ha = a3 * w1h[3][jp] + ha;
      ha = r4 * w1h[4][jp] + ha;
      ha = __builtin_elementwise_max(ha, z2);
      if (jp == 0) u.x = h2bits(ha); else u.y = h2bits(ha);
    }
    return u;
  };

  auto compute_chunk = [&](int c, int buf) {
#pragma unroll
    for (int nn = 0; nn < CH; ++nn) {
      const int n = c * CH + nn;
      uint2 bb = s_bb[n][jq];
      uint2 u = gemm1_row(n, tt, bb);
      *reinterpret_cast<uint2*>(&s_hid[buf][nn][0] + wbyte) = u;
      if (tt < 4) {
        uint2 u2 = gemm1_row(n, 16 + tt, bb);
        *reinterpret_cast<uint2*>(&s_hid[buf][nn][0] + wbyte2) = u2;
      }
    }
  };

  f32x4 rmax[4], rmax2[4];
#pragma unroll
  for (int jb = 0; jb < 4; ++jb) {
    rmax[jb] = f32x4{-3e38f, -3e38f, -3e38f, -3e38f};
    rmax2[jb] = f32x4{-3e38f, -3e38f, -3e38f, -3e38f};
  }

  auto mfma_step = [&](int buf) {
#pragma unroll
    for (int nn = 0; nn < CH; ++nn) {
      const char* slab = &s_hid[buf][nn][0];
      f16x8 A0 = *reinterpret_cast<const f16x8*>(slab + aoff0);
      f16x8 A1 = *reinterpret_cast<const f16x8*>(slab + aoff1);
      f16x8 A20 = *reinterpret_cast<const f16x8*>(slab + aoff2_0);
      f16x8 A21 = *reinterpret_cast<const f16x8*>(slab + aoff2_1);
#pragma unroll
      for (int jb = 0; jb < 4; ++jb) {
        f32x4 c = {0.f, 0.f, 0.f, 0.f};
        c = __builtin_amdgcn_mfma_f32_16x16x32_f16(A0, Bf[jb][0], c, 0, 0, 0);
        c = __builtin_amdgcn_mfma_f32_16x16x32_f16(A1, Bf[jb][1], c, 0, 0, 0);
        rmax[jb] = __builtin_elementwise_max(rmax[jb], c);
        f32x4 c2 = {0.f, 0.f, 0.f, 0.f};
        c2 = __builtin_amdgcn_mfma_f32_16x16x32_f16(A20, Bf[jb][0], c2, 0, 0, 0);
        c2 = __builtin_amdgcn_mfma_f32_16x16x32_f16(A21, Bf[jb][1], c2, 0, 0, 0);
        rmax2[jb] = __builtin_elementwise_max(rmax2[jb], c2);
      }
    }
  };

  __syncthreads();  // barrier 2: s_rel + s_bb ready
  compute_chunk(0, 0);
  __syncthreads();  // barrier 3: chunk 0 staged

  for (int c = 0; c < NCH; ++c) {
    if (c + 1 < NCH) compute_chunk(c + 1, (c + 1) & 1);
    mfma_step(c & 1);
    __syncthreads();
  }

  // ---- t-sum: main tile (all rows) + tail tile (kg==0 lanes hold t16-19) ---
  {
#pragma unroll
    for (int jb = 0; jb < 4; ++jb) {
      float s = (rmax[jb][0] + rmax[jb][1]) + (rmax[jb][2] + rmax[jb][3]);
      if (kg == 0)
        s += (rmax2[jb][0] + rmax2[jb][1]) + (rmax2[jb][2] + rmax2[jb][3]);
      s += __shfl_xor(s, 16);
      s += __shfl_xor(s, 32);
      if (lane < 16)
        ws_bm[p * 256 + wv * 64 + jb * 16 + lane] = s;
    }
  }
  if (tid == 0)
    ws_bm[WS_SC_OFF + p * 8 + 5] = s_cw[0] + s_cw[1] + s_cw[2] + s_cw[3];
}

// ---------------- kernel 2: combine + decoder + score (256 threads) ---------
__global__ void combine_kernel(const float* __restrict__ ws,
                               const float* __restrict__ enc_b2,
                               const float* __restrict__ dec_w1,
                               const float* __restrict__ dec_b1,
                               const float* __restrict__ dec_w2,
                               const float* __restrict__ dec_b2,
                               float* __restrict__ out_scores) {
  __shared__ float s_feat[256];
  __shared__ float s_dhp[4][64];
  __shared__ float s_dh[64];
  __shared__ float s_hard[4];
  __shared__ float s_inter[4];
  __shared__ float s_mc[2];
  const int bm = blockIdx.x;
  const int tid = threadIdx.x;  // 256 threads
  const float* wb = ws + WS_BASE + (size_t)bm * WS_BM_STRIDE;

  {
    int c = tid;
    float f = 0.f;
#pragma unroll
    for (int pp = 0; pp < NP; ++pp) f += wb[pp * 256 + c];
    s_feat[c] = f * (1.f / NT) + enc_b2[c];
  }
  const float* sc = wb + WS_SC_OFF;
  if (tid < 6) {
    float s = 0.f;
#pragma unroll
    for (int pp = 0; pp < NP; ++pp) s += sc[pp * 8 + tid];
    if (tid == 0) s_hard[0] = -fminf(fmaxf(s * (1.f / NT), 0.f), 15.f) * (1.f / 15.f);
    if (tid == 1) s_hard[1] = fminf(fmaxf(s * (1.f / NT), 0.f), 4.f) * 0.25f;
    if (tid == 2) s_hard[2] = fminf(fmaxf(s * (1.f / NT), 0.f), 6.f) * (1.f / 6.f);
    if (tid == 3) s_hard[3] = fminf(fmaxf(s * (1.f / NT), 0.f), 5.f) * 0.2f;
    if (tid == 4) s_mc[0] = s;
    if (tid == 5) s_mc[1] = s;
  }
  __syncthreads();

  // decoder layer 1: 4 groups x 64 rows of dec_w1, partial sums in LDS
  {
    const int q = tid >> 6, j = tid & 63;
    float a = 0.f;
#pragma unroll 8
    for (int i = 0; i < 64; ++i)
      a += s_feat[q * 64 + i] * dec_w1[(q * 64 + i) * 64 + j];
    s_dhp[q][j] = a;
  }
  __syncthreads();
  if (tid < 64) {
    float acc = dec_b1[tid] + ((s_dhp[0][tid] + s_dhp[1][tid]) +
                               (s_dhp[2][tid] + s_dhp[3][tid]));
    s_dh[tid] = acc > 0.f ? acc : expm1f(acc);  // elu
  }
  __syncthreads();

  if (tid < 4) {
    float acc = dec_b2[tid];
    for (int k = 0; k < 64; ++k) acc += s_dh[k] * dec_w2[k * 4 + tid];
    s_inter[tid] = 1.f / (1.f + __expf(-acc));  // sigmoid
  }
  __syncthreads();

  if (tid == 0) {
    const float* wts = ws + WS_WTS;
    float scv = 0.f;
#pragma unroll
    for (int i = 0; i < 4; ++i) scv += s_hard[i] * wts[i];
#pragma unroll
    for (int i = 0; i < 4; ++i) scv += s_inter[i] * wts[4 + i];
    scv = -scv - 10.f * s_mc[1];
    if (s_mc[0] == 0.f) scv = -INFINITY;
    out_scores[bm] = scv;
  }
}

extern "C" void kernel_launch(void* const* d_in, const int* in_sizes, int n_in,
                              void* d_out, int out_size, void* d_ws, size_t ws_size,
                              hipStream_t stream) {
  const float* ego_traj      = (const float*)d_in[0];
  const float* agents_traj   = (const float*)d_in[2];
  const float* agents_states = (const float*)d_in[3];
  const float* enc_w1 = (const float*)d_in[4];
  const float* enc_b1 = (const float*)d_in[5];
  const float* enc_w2 = (const float*)d_in[6];
  const float* enc_b2 = (const float*)d_in[7];
  const float* dec_w1 = (const float*)d_in[8];
  const float* dec_b1 = (const float*)d_in[9];
  const float* dec_w2 = (const float*)d_in[10];
  const float* dec_b2 = (const float*)d_in[11];
  const float* wd_w1 = (const float*)d_in[12];
  const float* wd_b1 = (const float*)d_in[13];
  const float* wd_w2 = (const float*)d_in[14];
  const float* wd_b2 = (const float*)d_in[15];

  float* out = (float*)d_out;
  float* ws = (float*)d_ws;

  prep_kernel<<<NB + 9, 256, 0, stream>>>(agents_states, enc_w1, enc_b1, enc_w2,
                                          wd_w1, wd_b1, wd_w2, wd_b2, ws, out);
  dim3 grid(NP, NB * NM);
  score_partial<<<grid, 256, 0, stream>>>(
      ego_traj, agents_traj, agents_states, enc_w1, ws);
  combine_kernel<<<NB * NM, 256, 0, stream>>>(
      ws, enc_b2, dec_w1, dec_b1, dec_w2, dec_b2, out);
}

// Round 20
// 49.551 us; speedup vs baseline: 1.5039x; 1.5039x over previous
//
#include <hip/hip_runtime.h>
#include <hip/hip_fp16.h>
#include <math.h>
#include <string.h>

typedef __attribute__((ext_vector_type(8))) short short8;
typedef __attribute__((ext_vector_type(8))) _Float16 f16x8;
typedef __attribute__((ext_vector_type(4))) _Float16 h4;
typedef __attribute__((ext_vector_type(2))) _Float16 h2;
typedef __attribute__((ext_vector_type(4))) float f32x4;

#define NB 16
#define NM 16
#define NN 32
#define NT 80
#define TC 20   // timesteps per partial block (16-row MFMA tile + 4-row tail tile)
#define NP 4    // partial blocks per (b,m): grid 1024 = exactly 4/CU, no tail round
#define CH 4    // agents per hidden chunk
#define NCH 8   // chunks (NN/CH)

// ---- d_ws float-slot layout ----
#define WS_WTS 0                 // 8 floats: softplus weights
#define WS_BF 16                 // 8192 float-slots: f16 frag table enc_w2 (32 KB)
#define WS_BB 8208               // 16384 float-slots: baseB[b][n][32 h2] (64 KB)
#define WS_BASE 24592            // partials, WS_BM_STRIDE per bm
#define WS_BM_STRIDE 1088        // NP*256 feat partials + 64 scalars
#define WS_SC_OFF 1024           // within-bm offset of scalar partials

__device__ __forceinline__ short f2h(float f) {
  _Float16 h = (_Float16)f;
  short s; memcpy(&s, &h, 2); return s;
}
__device__ __forceinline__ unsigned h2bits(h2 h) {
  unsigned u; memcpy(&u, &h, 4); return u;
}
__device__ __forceinline__ h2 bits2h(unsigned u) {
  h2 h; memcpy(&h, &u, 4); return h;
}

// ---------------- kernel 0: prep — f16 weight tables + weights head ----------
__global__ void prep_kernel(const float* __restrict__ agents_states,
                            const float* __restrict__ enc_w1,
                            const float* __restrict__ enc_b1,
                            const float* __restrict__ enc_w2,
                            const float* __restrict__ wd_w1,
                            const float* __restrict__ wd_b1,
                            const float* __restrict__ wd_w2,
                            const float* __restrict__ wd_b2,
                            float* __restrict__ ws,
                            float* __restrict__ out) {
  const int blk = blockIdx.x;
  const int tid = threadIdx.x;
  if (blk < NB) {
    // baseB[b][n][j] = enc_b1[j] + mask_n * (states[6:11] @ enc_w1[5:10,j]) -> h2
    __shared__ float smask[NN];
    if (tid < NN) {
      const float* st = agents_states + ((size_t)blk * NN + tid) * 11;
      float s = 0.f;
      for (int i = 0; i < 11; ++i) s += st[i];
      smask[tid] = (s != 0.f) ? 1.f : 0.f;
    }
    __syncthreads();
    h2* bb = reinterpret_cast<h2*>(ws + WS_BB) + blk * (NN * 32);
    for (int e = tid; e < NN * 32; e += 256) {   // e = n*32 + jpair
      int n = e >> 5, jp = e & 31;
      const float* st = agents_states + ((size_t)blk * NN + n) * 11 + 6;
      float v[2];
#pragma unroll
      for (int hh = 0; hh < 2; ++hh) {
        int j = jp * 2 + hh;
        float acc = st[0] * enc_w1[5 * 64 + j] + st[1] * enc_w1[6 * 64 + j] +
                    st[2] * enc_w1[7 * 64 + j] + st[3] * enc_w1[8 * 64 + j] +
                    st[4] * enc_w1[9 * 64 + j];
        v[hh] = smask[n] * acc + enc_b1[j];
      }
      h2 r; r[0] = (_Float16)v[0]; r[1] = (_Float16)v[1];
      bb[e] = r;
    }
  } else if (blk < NB + 8) {
    // Bf fragment table: 4 slots per block, 1 slot per wave group
    const int g = tid >> 6;
    const int lane = tid & 63;
    const int s = (blk - NB) * 4 + g;
    const int wv = s >> 3, jb = (s >> 1) & 3, kt = s & 1;
    const int col = wv * 64 + jb * 16 + (lane & 15);
    const int krow = (lane >> 4) * 8;
    short8 v;
#pragma unroll
    for (int j = 0; j < 8; ++j)
      v[j] = f2h(enc_w2[(kt * 32 + krow + j) * 256 + col]);
    reinterpret_cast<short8*>(ws + WS_BF)[s * 64 + lane] = v;
  } else {
    // weights head (enc_in = ones), 256 threads: 4 groups x 64 rows of wd_w1
    __shared__ float s_part[4][64];
    __shared__ float sh[64];
    const int g = tid >> 6, j = tid & 63;
    {
      float a = 0.f;
#pragma unroll 8
      for (int i = 0; i < 64; ++i)
        a += wd_w1[(g * 64 + i) * 64 + j];
      s_part[g][j] = a;
    }
    __syncthreads();
    if (tid < 64) {
      float acc = wd_b1[tid] + ((s_part[0][tid] + s_part[1][tid]) +
                                (s_part[2][tid] + s_part[3][tid]));
      sh[tid] = acc > 0.f ? acc : expm1f(acc);  // elu
    }
    __syncthreads();
    if (tid < 8) {
      float acc = wd_b2[tid];
      for (int k = 0; k < 64; ++k) acc += sh[k] * wd_w2[k * 8 + tid];
      float sp = log1pf(__expf(acc));  // softplus
      ws[WS_WTS + tid] = sp;
      for (int b = 0; b < NB; ++b) out[NB * NM + b * 8 + tid] = sp;
    }
  }
}

// ---------------- kernel 1: t-on-rows partial kernel, TC=20 -----------------
// R19 structure with __launch_bounds__(256,2): the (256,4) bound pinned VGPRs
// at 64 and spilled (FETCH 100MB). Body needs ~100-120 VGPR; <=128 keeps
// 4 blocks/CU residency (16 waves), which with grid=1024 means zero tail round.
__global__ __launch_bounds__(256, 2) void score_partial(
    const float* __restrict__ ego_traj,      // [B][M][T][6]
    const float* __restrict__ agents_traj,   // [B][M][N][T][3]
    const float* __restrict__ agents_states, // [B][N][11]
    const float* __restrict__ enc_w1,        // [10][64]
    float* __restrict__ ws)
{
  __shared__ h4 s_r01[NN][TC];                         // (f0,f0,f1,f1) per (n,t)
  __shared__ h4 s_r23[NN][TC];                         // (f2,f2,f3,f3)
  __shared__ h2 s_r4[NN][TC];                          // (f4,f4)
  __shared__ uint2 s_bb[NN][16];                       // baseB j-quads, 4 KB
  __shared__ __align__(16) char s_hid[2][CH][TC * 128];// 20 KB dbuf f16 tile
  __shared__ float s_ego[TC][5];
  __shared__ float s_acc[TC + 2];
  __shared__ float s_spd[TC], s_lat[TC], s_egos[TC];
  __shared__ float s_mask[NN];
  __shared__ float s_cw[4];

  const int p = blockIdx.x;
  const int bm = blockIdx.y;
  const int t0 = p * TC;
  const int b = bm >> 4;
  const int tid = threadIdx.x;
  const int lane = tid & 63;
  const int wv = tid >> 6;

  float* ws_bm = ws + WS_BASE + (size_t)bm * WS_BM_STRIDE;

  // ---- phase A: ego staging + agent mask + baseB LDS stage ----
  if (tid < TC) {
    int i = tid;
    const float* e = ego_traj + ((size_t)bm * NT + (t0 + i)) * 6;
    float ex = e[0], ey = e[1], eh = e[2], spd = e[3], acc = e[4], cur = e[5];
    s_ego[i][0] = ex; s_ego[i][1] = ey; s_ego[i][2] = eh;
    s_ego[i][3] = spd * __cosf(eh);
    s_ego[i][4] = spd * __sinf(eh);
    s_spd[i] = spd;
    s_acc[i + 1] = acc;
    s_lat[i] = fabsf(spd * spd * cur);
    s_egos[i] = ex + ey + eh + spd + acc + cur;
  } else if (tid == TC) {
    int tp = (p == 0) ? 0 : (t0 - 1);
    s_acc[0] = ego_traj[((size_t)bm * NT + tp) * 6 + 4];
  } else if (tid >= 64 && tid < 64 + NN) {
    int n = tid - 64;
    const float* st = agents_states + ((size_t)b * NN + n) * 11;
    float s = 0.f;
    for (int i = 0; i < 11; ++i) s += st[i];
    s_mask[n] = (s != 0.f) ? 1.f : 0.f;
  }
  {
    const uint2* bbt = reinterpret_cast<const uint2*>(ws + WS_BB) + b * 512;
#pragma unroll
    for (int k = 0; k < 2; ++k) {
      int e = tid + k * 256;                 // 512 = NN*16 j-quads
      s_bb[e >> 4][e & 15] = bbt[e];
    }
  }

  const int jq = tid >> 4;        // j-quad (0..15, global across block)
  const int tt = tid & 15;        // GEMM1 main row (local t 0..15)
  const int j0g = jq * 4;

  f16x8 Bf[4][2];
  {
    const f16x8* bft = reinterpret_cast<const f16x8*>(ws + WS_BF);
#pragma unroll
    for (int jb = 0; jb < 4; ++jb)
#pragma unroll
      for (int kt = 0; kt < 2; ++kt)
        Bf[jb][kt] = bft[((wv * 4 + jb) * 2 + kt) * 64 + lane];
  }

  h2 w1h[5][2];
#pragma unroll
  for (int f = 0; f < 5; ++f)
#pragma unroll
    for (int jp = 0; jp < 2; ++jp) {
      h2 r;
      r[0] = (_Float16)enc_w1[f * 64 + j0g + jp * 2];
      r[1] = (_Float16)enc_w1[f * 64 + j0g + jp * 2 + 1];
      w1h[f][jp] = r;
    }
  __syncthreads();  // barrier 1: s_ego/s_mask ready

  // ---- phase B: rel features for 32n x 20t (640 pairs) + coll ----
  {
    float collacc = 0.f;
    const float* atraj = agents_traj + (size_t)bm * (NN * NT * 3);
#pragma unroll
    for (int k = 0; k < 3; ++k) {
      int pp = tid + k * 256;
      if (pp < NN * TC) {
        int n = pp / TC;
        int i = pp - n * TC;
        int tg = t0 + i;
        const float* bp = atraj + n * (NT * 3) + tg * 3;
        float ax = bp[0], ay = bp[1], ah = bp[2];
        float avx, avy;
        if (tg == 0) { avx = (bp[3] - ax) * 10.f; avy = (bp[4] - ay) * 10.f; }
        else         { avx = (ax - bp[-3]) * 10.f; avy = (ay - bp[-2]) * 10.f; }
        float ex = s_ego[i][0], ey = s_ego[i][1], eh = s_ego[i][2];
        float evx = s_ego[i][3], evy = s_ego[i][4];
        float m = s_mask[n];
        float ryr = ah - eh;
        float w = ryr - 6.283185307179586f * rintf(ryr * 0.15915494309189535f);
        float cy = __cosf(ryr), sy = __sinf(ryr);
        float dx = ax - ex, dy = ay - ey;
        float r0 = dx * cy * m, r1 = dy * sy * m, r2 = w * m;
        float r3 = (avx - evx) * cy * m, r4 = (avy - evy) * sy * m;
        h4 v01, v23; h2 v4;
        v01[0] = v01[1] = (_Float16)r0; v01[2] = v01[3] = (_Float16)r1;
        v23[0] = v23[1] = (_Float16)r2; v23[2] = v23[3] = (_Float16)r3;
        v4[0] = v4[1] = (_Float16)r4;
        s_r01[n][i] = v01;
        s_r23[n][i] = v23;
        s_r4[n][i] = v4;
        collacc += __expf(-0.2f * (dx * dx + dy * dy)) * m;
      }
    }
#pragma unroll
    for (int off = 1; off < 64; off <<= 1) collacc += __shfl_xor(collacc, off);
    if (lane == 0) s_cw[wv] = collacc;
  }

  // hard-feature partial sums on high tids
  if (tid >= 251) {
    int which = tid - 251;
    float s = 0.f;
    if (which == 0)      { for (int i = 0; i < TC; ++i) s += s_spd[i]; }
    else if (which == 1) { for (int i = 0; i < TC; ++i) s += fabsf(s_acc[i + 1]); }
    else if (which == 2) {
      for (int i = 0; i < TC; ++i) {
        int ia = (p == 0 && i == 0) ? 2 : (i + 1);
        s += fabsf((s_acc[ia] - s_acc[ia - 1]) * 10.f);
      }
    }
    else if (which == 3) { for (int i = 0; i < TC; ++i) s += s_lat[i]; }
    else                 { for (int i = 0; i < TC; ++i) s += s_egos[i]; }
    ws_bm[WS_SC_OFF + p * 8 + which] = s;
  }

  // A-read offsets: main tile rows = lane&15; tail tile rows = 16 + (tl&3)
  const int tl = lane & 15, kg = lane >> 4;
  const int swr = (tl & 7) << 4;
  const int aoff0 = tl * 128 + ((kg * 16) ^ swr);
  const int aoff1 = tl * 128 + ((64 + kg * 16) ^ swr);
  const int tl4 = tl & 3;
  const int swr2 = tl4 << 4;                      // (16+tl4)&7 == tl4
  const int aoff2_0 = (16 + tl4) * 128 + ((kg * 16) ^ swr2);
  const int aoff2_1 = (16 + tl4) * 128 + ((64 + kg * 16) ^ swr2);
  const int wbyte  = tt * 128 + ((jq * 8) ^ ((tt & 7) << 4));
  const int wbyte2 = (16 + tt) * 128 + ((jq * 8) ^ ((tt & 7) << 4));

  h2 z2; z2[0] = z2[1] = (_Float16)0.f;

  auto gemm1_row = [&](int n, int i, uint2 bb) -> uint2 {
    h4 r01 = s_r01[n][i];
    h4 r23 = s_r23[n][i];
    h2 r4 = s_r4[n][i];
    h2 a0 = __builtin_shufflevector(r01, r01, 0, 1);
    h2 a1 = __builtin_shufflevector(r01, r01, 2, 3);
    h2 a2 = __builtin_shufflevector(r23, r23, 0, 1);
    h2 a3 = __builtin_shufflevector(r23, r23, 2, 3);
    uint2 u;
#pragma unroll
    for (int jp = 0; jp < 2; ++jp) {
      h2 ha = bits2h(jp ? bb.y : bb.x);
      ha = a0 * w1h[0][jp] + ha;
      ha = a1 * w1h[1][jp] + ha;
      ha = a2 * w1h[2][jp] + ha;
      ha = a3 * w1h[3][jp] + ha;
      ha = r4 * w1h[4][jp] + ha;
      ha = __builtin_elementwise_max(ha, z2);
      if (jp == 0) u.x = h2bits(ha); else u.y = h2bits(ha);
    }
    return u;
  };

  auto compute_chunk = [&](int c, int buf) {
#pragma unroll
    for (int nn = 0; nn < CH; ++nn) {
      const int n = c * CH + nn;
      uint2 bb = s_bb[n][jq];
      uint2 u = gemm1_row(n, tt, bb);
      *reinterpret_cast<uint2*>(&s_hid[buf][nn][0] + wbyte) = u;
      if (tt < 4) {
        uint2 u2 = gemm1_row(n, 16 + tt, bb);
        *reinterpret_cast<uint2*>(&s_hid[buf][nn][0] + wbyte2) = u2;
      }
    }
  };

  f32x4 rmax[4], rmax2[4];
#pragma unroll
  for (int jb = 0; jb < 4; ++jb) {
    rmax[jb] = f32x4{-3e38f, -3e38f, -3e38f, -3e38f};
    rmax2[jb] = f32x4{-3e38f, -3e38f, -3e38f, -3e38f};
  }

  auto mfma_step = [&](int buf) {
#pragma unroll
    for (int nn = 0; nn < CH; ++nn) {
      const char* slab = &s_hid[buf][nn][0];
      f16x8 A0 = *reinterpret_cast<const f16x8*>(slab + aoff0);
      f16x8 A1 = *reinterpret_cast<const f16x8*>(slab + aoff1);
      f16x8 A20 = *reinterpret_cast<const f16x8*>(slab + aoff2_0);
      f16x8 A21 = *reinterpret_cast<const f16x8*>(slab + aoff2_1);
#pragma unroll
      for (int jb = 0; jb < 4; ++jb) {
        f32x4 c = {0.f, 0.f, 0.f, 0.f};
        c = __builtin_amdgcn_mfma_f32_16x16x32_f16(A0, Bf[jb][0], c, 0, 0, 0);
        c = __builtin_amdgcn_mfma_f32_16x16x32_f16(A1, Bf[jb][1], c, 0, 0, 0);
        rmax[jb] = __builtin_elementwise_max(rmax[jb], c);
        f32x4 c2 = {0.f, 0.f, 0.f, 0.f};
        c2 = __builtin_amdgcn_mfma_f32_16x16x32_f16(A20, Bf[jb][0], c2, 0, 0, 0);
        c2 = __builtin_amdgcn_mfma_f32_16x16x32_f16(A21, Bf[jb][1], c2, 0, 0, 0);
        rmax2[jb] = __builtin_elementwise_max(rmax2[jb], c2);
      }
    }
  };

  __syncthreads();  // barrier 2: s_rel + s_bb ready
  compute_chunk(0, 0);
  __syncthreads();  // barrier 3: chunk 0 staged

  for (int c = 0; c < NCH; ++c) {
    if (c + 1 < NCH) compute_chunk(c + 1, (c + 1) & 1);
    mfma_step(c & 1);
    __syncthreads();
  }

  // ---- t-sum: main tile (all rows) + tail tile (kg==0 lanes hold t16-19) ---
  {
#pragma unroll
    for (int jb = 0; jb < 4; ++jb) {
      float s = (rmax[jb][0] + rmax[jb][1]) + (rmax[jb][2] + rmax[jb][3]);
      if (kg == 0)
        s += (rmax2[jb][0] + rmax2[jb][1]) + (rmax2[jb][2] + rmax2[jb][3]);
      s += __shfl_xor(s, 16);
      s += __shfl_xor(s, 32);
      if (lane < 16)
        ws_bm[p * 256 + wv * 64 + jb * 16 + lane] = s;
    }
  }
  if (tid == 0)
    ws_bm[WS_SC_OFF + p * 8 + 5] = s_cw[0] + s_cw[1] + s_cw[2] + s_cw[3];
}

// ---------------- kernel 2: combine + decoder + score (256 threads) ---------
__global__ void combine_kernel(const float* __restrict__ ws,
                               const float* __restrict__ enc_b2,
                               const float* __restrict__ dec_w1,
                               const float* __restrict__ dec_b1,
                               const float* __restrict__ dec_w2,
                               const float* __restrict__ dec_b2,
                               float* __restrict__ out_scores) {
  __shared__ float s_feat[256];
  __shared__ float s_dhp[4][64];
  __shared__ float s_dh[64];
  __shared__ float s_hard[4];
  __shared__ float s_inter[4];
  __shared__ float s_mc[2];
  const int bm = blockIdx.x;
  const int tid = threadIdx.x;  // 256 threads
  const float* wb = ws + WS_BASE + (size_t)bm * WS_BM_STRIDE;

  {
    int c = tid;
    float f = 0.f;
#pragma unroll
    for (int pp = 0; pp < NP; ++pp) f += wb[pp * 256 + c];
    s_feat[c] = f * (1.f / NT) + enc_b2[c];
  }
  const float* sc = wb + WS_SC_OFF;
  if (tid < 6) {
    float s = 0.f;
#pragma unroll
    for (int pp = 0; pp < NP; ++pp) s += sc[pp * 8 + tid];
    if (tid == 0) s_hard[0] = -fminf(fmaxf(s * (1.f / NT), 0.f), 15.f) * (1.f / 15.f);
    if (tid == 1) s_hard[1] = fminf(fmaxf(s * (1.f / NT), 0.f), 4.f) * 0.25f;
    if (tid == 2) s_hard[2] = fminf(fmaxf(s * (1.f / NT), 0.f), 6.f) * (1.f / 6.f);
    if (tid == 3) s_hard[3] = fminf(fmaxf(s * (1.f / NT), 0.f), 5.f) * 0.2f;
    if (tid == 4) s_mc[0] = s;
    if (tid == 5) s_mc[1] = s;
  }
  __syncthreads();

  // decoder layer 1: 4 groups x 64 rows of dec_w1, partial sums in LDS
  {
    const int q = tid >> 6, j = tid & 63;
    float a = 0.f;
#pragma unroll 8
    for (int i = 0; i < 64; ++i)
      a += s_feat[q * 64 + i] * dec_w1[(q * 64 + i) * 64 + j];
    s_dhp[q][j] = a;
  }
  __syncthreads();
  if (tid < 64) {
    float acc = dec_b1[tid] + ((s_dhp[0][tid] + s_dhp[1][tid]) +
                               (s_dhp[2][tid] + s_dhp[3][tid]));
    s_dh[tid] = acc > 0.f ? acc : expm1f(acc);  // elu
  }
  __syncthreads();

  if (tid < 4) {
    float acc = dec_b2[tid];
    for (int k = 0; k < 64; ++k) acc += s_dh[k] * dec_w2[k * 4 + tid];
    s_inter[tid] = 1.f / (1.f + __expf(-acc));  // sigmoid
  }
  __syncthreads();

  if (tid == 0) {
    const float* wts = ws + WS_WTS;
    float scv = 0.f;
#pragma unroll
    for (int i = 0; i < 4; ++i) scv += s_hard[i] * wts[i];
#pragma unroll
    for (int i = 0; i < 4; ++i) scv += s_inter[i] * wts[4 + i];
    scv = -scv - 10.f * s_mc[1];
    if (s_mc[0] == 0.f) scv = -INFINITY;
    out_scores[bm] = scv;
  }
}

extern "C" void kernel_launch(void* const* d_in, const int* in_sizes, int n_in,
                              void* d_out, int out_size, void* d_ws, size_t ws_size,
                              hipStream_t stream) {
  const float* ego_traj      = (const float*)d_in[0];
  const float* agents_traj   = (const float*)d_in[2];
  const float* agents_states = (const float*)d_in[3];
  const float* enc_w1 = (const float*)d_in[4];
  const float* enc_b1 = (const float*)d_in[5];
  const float* enc_w2 = (const float*)d_in[6];
  const float* enc_b2 = (const float*)d_in[7];
  const float* dec_w1 = (const float*)d_in[8];
  const float* dec_b1 = (const float*)d_in[9];
  const float* dec_w2 = (const float*)d_in[10];
  const float* dec_b2 = (const float*)d_in[11];
  const float* wd_w1 = (const float*)d_in[12];
  const float* wd_b1 = (const float*)d_in[13];
  const float* wd_w2 = (const float*)d_in[14];
  const float* wd_b2 = (const float*)d_in[15];

  float* out = (float*)d_out;
  float* ws = (float*)d_ws;

  prep_kernel<<<NB + 9, 256, 0, stream>>>(agents_states, enc_w1, enc_b1, enc_w2,
                                          wd_w1, wd_b1, wd_w2, wd_b2, ws, out);
  dim3 grid(NP, NB * NM);
  score_partial<<<grid, 256, 0, stream>>>(
      ego_traj, agents_traj, agents_states, enc_w1, ws);
  combine_kernel<<<NB * NM, 256, 0, stream>>>(
      ws, enc_b2, dec_w1, dec_b1, dec_w2, dec_b2, out);
}

// Round 21
// 40.546 us; speedup vs baseline: 1.8379x; 1.2221x over previous
//
#include <hip/hip_runtime.h>
#include <hip/hip_fp16.h>
#include <math.h>
#include <string.h>

typedef __attribute__((ext_vector_type(8))) short short8;
typedef __attribute__((ext_vector_type(8))) _Float16 f16x8;
typedef __attribute__((ext_vector_type(2))) _Float16 h2;
typedef __attribute__((ext_vector_type(4))) float f32x4;

#define NB 16
#define NM 16
#define NN 32
#define NT 80
#define TC 16   // timesteps per partial block (= MFMA row-tile)
#define NP 5    // partial blocks per (b,m)
#define CH 4    // agents per hidden chunk
#define NCH 8   // chunks (NN/CH)

// ---- d_ws float-slot layout ----
#define WS_WTS 0                 // 8 floats: softplus weights
#define WS_BF 16                 // 8192 float-slots: f16 frag table enc_w2 (32 KB)
#define WS_BB 8208               // 16384 float-slots: baseB[b][n][32 h2] (64 KB)
#define WS_BASE 24592            // partials, WS_BM_STRIDE per bm
#define WS_BM_STRIDE 1344        // NP*256 feat partials + 64 scalars
#define WS_SC_OFF 1280           // within-bm offset of scalar partials

__device__ __forceinline__ short f2h(float f) {
  _Float16 h = (_Float16)f;
  short s; memcpy(&s, &h, 2); return s;
}
__device__ __forceinline__ unsigned h2bits(h2 h) {
  unsigned u; memcpy(&u, &h, 4); return u;
}
__device__ __forceinline__ h2 bits2h(unsigned u) {
  h2 h; memcpy(&h, &u, 4); return h;
}

// ---------------- kernel 0: prep — f16 weight tables + weights head ----------
// blocks 0..15: baseB for b = blk. blocks 16..23: Bf table, 4 slots each.
// block 24: weights head (256-thread split).
__global__ void prep_kernel(const float* __restrict__ agents_states,
                            const float* __restrict__ enc_w1,
                            const float* __restrict__ enc_b1,
                            const float* __restrict__ enc_w2,
                            const float* __restrict__ wd_w1,
                            const float* __restrict__ wd_b1,
                            const float* __restrict__ wd_w2,
                            const float* __restrict__ wd_b2,
                            float* __restrict__ ws,
                            float* __restrict__ out) {
  const int blk = blockIdx.x;
  const int tid = threadIdx.x;
  if (blk < NB) {
    // baseB[b][n][j] = enc_b1[j] + mask_n * (states[6:11] @ enc_w1[5:10,j]) -> h2
    __shared__ float smask[NN];
    if (tid < NN) {
      const float* st = agents_states + ((size_t)blk * NN + tid) * 11;
      float s = 0.f;
      for (int i = 0; i < 11; ++i) s += st[i];
      smask[tid] = (s != 0.f) ? 1.f : 0.f;
    }
    __syncthreads();
    h2* bb = reinterpret_cast<h2*>(ws + WS_BB) + blk * (NN * 32);
    for (int e = tid; e < NN * 32; e += 256) {   // e = n*32 + jpair
      int n = e >> 5, jp = e & 31;
      const float* st = agents_states + ((size_t)blk * NN + n) * 11 + 6;
      float v[2];
#pragma unroll
      for (int hh = 0; hh < 2; ++hh) {
        int j = jp * 2 + hh;
        float acc = st[0] * enc_w1[5 * 64 + j] + st[1] * enc_w1[6 * 64 + j] +
                    st[2] * enc_w1[7 * 64 + j] + st[3] * enc_w1[8 * 64 + j] +
                    st[4] * enc_w1[9 * 64 + j];
        v[hh] = smask[n] * acc + enc_b1[j];
      }
      h2 r; r[0] = (_Float16)v[0]; r[1] = (_Float16)v[1];
      bb[e] = r;
    }
  } else if (blk < NB + 8) {
    // Bf fragment table: 4 slots per block, 1 slot per wave group
    const int g = tid >> 6;
    const int lane = tid & 63;
    const int s = (blk - NB) * 4 + g;
    const int wv = s >> 3, jb = (s >> 1) & 3, kt = s & 1;
    const int col = wv * 64 + jb * 16 + (lane & 15);
    const int krow = (lane >> 4) * 8;
    short8 v;
#pragma unroll
    for (int j = 0; j < 8; ++j)
      v[j] = f2h(enc_w2[(kt * 32 + krow + j) * 256 + col]);
    reinterpret_cast<short8*>(ws + WS_BF)[s * 64 + lane] = v;
  } else {
    // weights head (enc_in = ones), 256 threads: 4 groups x 64 rows of wd_w1
    __shared__ float s_part[4][64];
    __shared__ float sh[64];
    const int g = tid >> 6, j = tid & 63;
    {
      float a = 0.f;
#pragma unroll 8
      for (int i = 0; i < 64; ++i)
        a += wd_w1[(g * 64 + i) * 64 + j];
      s_part[g][j] = a;
    }
    __syncthreads();
    if (tid < 64) {
      float acc = wd_b1[tid] + ((s_part[0][tid] + s_part[1][tid]) +
                                (s_part[2][tid] + s_part[3][tid]));
      sh[tid] = acc > 0.f ? acc : expm1f(acc);  // elu
    }
    __syncthreads();
    if (tid < 8) {
      float acc = wd_b2[tid];
      for (int k = 0; k < 64; ++k) acc += sh[k] * wd_w2[k * 8 + tid];
      float sp = log1pf(__expf(acc));  // softplus
      ws[WS_WTS + tid] = sp;
      for (int b = 0; b < NB; ++b) out[NB * NM + b * 8 + tid] = sp;
    }
  }
}

// ---------------- kernel 1: t-on-rows partial kernel (R18 core, packed rel) -
// LDS-instruction reduction: rel features packed as ONE b128 (r0r0r1r1r2r2r3r3)
// + ONE b32 (r4r4) -> 2 LDS reads per (agent,thread) in GEMM1 instead of 3.
__global__ __launch_bounds__(256, 4) void score_partial(
    const float* __restrict__ ego_traj,      // [B][M][T][6]
    const float* __restrict__ agents_traj,   // [B][M][N][T][3]
    const float* __restrict__ agents_states, // [B][N][11]
    const float* __restrict__ enc_w1,        // [10][64]
    float* __restrict__ ws)
{
  __shared__ __align__(16) _Float16 s_rel8[NN][TC][8]; // packed b128/pair, 8 KB
  __shared__ h2 s_rel2[NN][TC];                        // (f4,f4), 2 KB
  __shared__ uint2 s_bb[NN][16];                       // baseB j-quads, 4 KB
  __shared__ __align__(16) char s_hid[2][CH][TC * 128];// 16 KB dbuf f16 tile
  __shared__ float s_ego[TC][5];
  __shared__ float s_acc[TC + 2];
  __shared__ float s_spd[TC], s_lat[TC], s_egos[TC];
  __shared__ float s_mask[NN];
  __shared__ float s_cw[4];

  const int p = blockIdx.x;
  const int bm = blockIdx.y;
  const int t0 = p * TC;
  const int b = bm >> 4;
  const int tid = threadIdx.x;
  const int lane = tid & 63;
  const int wv = tid >> 6;

  float* ws_bm = ws + WS_BASE + (size_t)bm * WS_BM_STRIDE;

  // ---- phase A: ego staging + agent mask + baseB LDS stage ----
  if (tid < TC) {
    int i = tid;
    const float* e = ego_traj + ((size_t)bm * NT + (t0 + i)) * 6;
    float ex = e[0], ey = e[1], eh = e[2], spd = e[3], acc = e[4], cur = e[5];
    s_ego[i][0] = ex; s_ego[i][1] = ey; s_ego[i][2] = eh;
    s_ego[i][3] = spd * __cosf(eh);
    s_ego[i][4] = spd * __sinf(eh);
    s_spd[i] = spd;
    s_acc[i + 1] = acc;
    s_lat[i] = fabsf(spd * spd * cur);
    s_egos[i] = ex + ey + eh + spd + acc + cur;
  } else if (tid == TC) {
    int tp = (p == 0) ? 0 : (t0 - 1);
    s_acc[0] = ego_traj[((size_t)bm * NT + tp) * 6 + 4];
  } else if (tid >= 64 && tid < 64 + NN) {
    int n = tid - 64;
    const float* st = agents_states + ((size_t)b * NN + n) * 11;
    float s = 0.f;
    for (int i = 0; i < 11; ++i) s += st[i];
    s_mask[n] = (s != 0.f) ? 1.f : 0.f;
  }
  {
    const uint2* bbt = reinterpret_cast<const uint2*>(ws + WS_BB) + b * 512;
#pragma unroll
    for (int k = 0; k < 2; ++k) {
      int e = tid + k * 256;                 // 512 = NN*16 j-quads
      s_bb[e >> 4][e & 15] = bbt[e];
    }
  }

  const int jq = tid & 15;        // j-quad within 64-col wave slice
  const int tt = tid >> 4;        // GEMM1 row (local t), 0..15
  const int j0 = jq * 4;

  f16x8 Bf[4][2];
  {
    const f16x8* bft = reinterpret_cast<const f16x8*>(ws + WS_BF);
#pragma unroll
    for (int jb = 0; jb < 4; ++jb)
#pragma unroll
      for (int kt = 0; kt < 2; ++kt)
        Bf[jb][kt] = bft[((wv * 4 + jb) * 2 + kt) * 64 + lane];
  }

  h2 w1h[5][2];
#pragma unroll
  for (int f = 0; f < 5; ++f)
#pragma unroll
    for (int jp = 0; jp < 2; ++jp) {
      h2 r;
      r[0] = (_Float16)enc_w1[f * 64 + j0 + jp * 2];
      r[1] = (_Float16)enc_w1[f * 64 + j0 + jp * 2 + 1];
      w1h[f][jp] = r;
    }
  __syncthreads();  // barrier 1: s_ego/s_mask ready

  // ---- phase B: packed rel features for 32n x 16t (2/thread) + coll ----
  {
    float collacc = 0.f;
    const float* atraj = agents_traj + (size_t)bm * (NN * NT * 3);
#pragma unroll
    for (int k = 0; k < 2; ++k) {
      int pp = tid + k * 256;                // 512 pairs exactly
      int n = pp >> 4;
      int i = pp & 15;
      int tg = t0 + i;
      const float* bp = atraj + n * (NT * 3) + tg * 3;
      float ax = bp[0], ay = bp[1], ah = bp[2];
      float avx, avy;
      if (tg == 0) { avx = (bp[3] - ax) * 10.f; avy = (bp[4] - ay) * 10.f; }
      else         { avx = (ax - bp[-3]) * 10.f; avy = (ay - bp[-2]) * 10.f; }
      float ex = s_ego[i][0], ey = s_ego[i][1], eh = s_ego[i][2];
      float evx = s_ego[i][3], evy = s_ego[i][4];
      float m = s_mask[n];
      float ryr = ah - eh;
      float w = ryr - 6.283185307179586f * rintf(ryr * 0.15915494309189535f);
      float cy = __cosf(ryr), sy = __sinf(ryr);
      float dx = ax - ex, dy = ay - ey;
      _Float16 r0 = (_Float16)(dx * cy * m);
      _Float16 r1 = (_Float16)(dy * sy * m);
      _Float16 r2 = (_Float16)(w * m);
      _Float16 r3 = (_Float16)((avx - evx) * cy * m);
      _Float16 r4 = (_Float16)((avy - evy) * sy * m);
      f16x8 v8;
      v8[0] = r0; v8[1] = r0; v8[2] = r1; v8[3] = r1;
      v8[4] = r2; v8[5] = r2; v8[6] = r3; v8[7] = r3;
      *reinterpret_cast<f16x8*>(&s_rel8[n][i][0]) = v8;
      h2 v4; v4[0] = r4; v4[1] = r4;
      s_rel2[n][i] = v4;
      collacc += __expf(-0.2f * (dx * dx + dy * dy)) * m;
    }
#pragma unroll
    for (int off = 1; off < 64; off <<= 1) collacc += __shfl_xor(collacc, off);
    if (lane == 0) s_cw[wv] = collacc;
  }

  // hard-feature partial sums on high tids
  if (tid >= 251) {
    int which = tid - 251;
    float s = 0.f;
    if (which == 0)      { for (int i = 0; i < TC; ++i) s += s_spd[i]; }
    else if (which == 1) { for (int i = 0; i < TC; ++i) s += fabsf(s_acc[i + 1]); }
    else if (which == 2) {
      for (int i = 0; i < TC; ++i) {
        int ia = (p == 0 && i == 0) ? 2 : (i + 1);
        s += fabsf((s_acc[ia] - s_acc[ia - 1]) * 10.f);
      }
    }
    else if (which == 3) { for (int i = 0; i < TC; ++i) s += s_lat[i]; }
    else                 { for (int i = 0; i < TC; ++i) s += s_egos[i]; }
    ws_bm[WS_SC_OFF + p * 8 + which] = s;
  }

  // A-read offsets (t-on-rows): lane -> (row=t=lane&15, kgroup=lane>>4)
  const int tl = lane & 15, kg = lane >> 4;
  const int swr = (tl & 7) << 4;
  const int aoff0 = tl * 128 + ((kg * 16) ^ swr);
  const int aoff1 = tl * 128 + ((64 + kg * 16) ^ swr);
  const int wbyte = tt * 128 + ((jq * 8) ^ ((tt & 7) << 4));

  h2 z2; z2[0] = z2[1] = (_Float16)0.f;

  auto compute_chunk = [&](int c, int buf) {
#pragma unroll
    for (int nn = 0; nn < CH; ++nn) {
      const int n = c * CH + nn;
      f16x8 r8 = *reinterpret_cast<const f16x8*>(&s_rel8[n][tt][0]);
      h2 r4 = s_rel2[n][tt];
      uint2 bb = s_bb[n][jq];
      h2 a0 = __builtin_shufflevector(r8, r8, 0, 1);
      h2 a1 = __builtin_shufflevector(r8, r8, 2, 3);
      h2 a2 = __builtin_shufflevector(r8, r8, 4, 5);
      h2 a3 = __builtin_shufflevector(r8, r8, 6, 7);
      uint2 u;
#pragma unroll
      for (int jp = 0; jp < 2; ++jp) {
        h2 ha = bits2h(jp ? bb.y : bb.x);
        ha = a0 * w1h[0][jp] + ha;
        ha = a1 * w1h[1][jp] + ha;
        ha = a2 * w1h[2][jp] + ha;
        ha = a3 * w1h[3][jp] + ha;
        ha = r4 * w1h[4][jp] + ha;
        ha = __builtin_elementwise_max(ha, z2);
        if (jp == 0) u.x = h2bits(ha); else u.y = h2bits(ha);
      }
      *reinterpret_cast<uint2*>(&s_hid[buf][nn][0] + wbyte) = u;
    }
  };

  f32x4 rmax[4];
#pragma unroll
  for (int jb = 0; jb < 4; ++jb)
    rmax[jb] = f32x4{-3e38f, -3e38f, -3e38f, -3e38f};

  auto mfma_step = [&](int buf) {
#pragma unroll
    for (int nn = 0; nn < CH; ++nn) {
      const char* slab = &s_hid[buf][nn][0];
      f16x8 A0 = *reinterpret_cast<const f16x8*>(slab + aoff0);
      f16x8 A1 = *reinterpret_cast<const f16x8*>(slab + aoff1);
#pragma unroll
      for (int jb = 0; jb < 4; ++jb) {
        f32x4 c = {0.f, 0.f, 0.f, 0.f};
        c = __builtin_amdgcn_mfma_f32_16x16x32_f16(A0, Bf[jb][0], c, 0, 0, 0);
        c = __builtin_amdgcn_mfma_f32_16x16x32_f16(A1, Bf[jb][1], c, 0, 0, 0);
        rmax[jb] = __builtin_elementwise_max(rmax[jb], c);
      }
    }
  };

  __syncthreads();  // barrier 2: s_rel + s_bb ready
  compute_chunk(0, 0);
  __syncthreads();  // barrier 3: chunk 0 staged

  for (int c = 0; c < NCH; ++c) {
    if (c + 1 < NCH) compute_chunk(c + 1, (c + 1) & 1);
    mfma_step(c & 1);
    __syncthreads();
  }

  // ---- t-sum (rows are t) + partial outputs ----
  {
#pragma unroll
    for (int jb = 0; jb < 4; ++jb) {
      float s = (rmax[jb][0] + rmax[jb][1]) + (rmax[jb][2] + rmax[jb][3]);
      s += __shfl_xor(s, 16);
      s += __shfl_xor(s, 32);
      if (lane < 16)
        ws_bm[p * 256 + wv * 64 + jb * 16 + lane] = s;
    }
  }
  if (tid == 0)
    ws_bm[WS_SC_OFF + p * 8 + 5] = s_cw[0] + s_cw[1] + s_cw[2] + s_cw[3];
}

// ---------------- kernel 2: combine + decoder + score (256 threads) ---------
__global__ void combine_kernel(const float* __restrict__ ws,
                               const float* __restrict__ enc_b2,
                               const float* __restrict__ dec_w1,
                               const float* __restrict__ dec_b1,
                               const float* __restrict__ dec_w2,
                               const float* __restrict__ dec_b2,
                               float* __restrict__ out_scores) {
  __shared__ float s_feat[256];
  __shared__ float s_dhp[4][64];
  __shared__ float s_dh[64];
  __shared__ float s_hard[4];
  __shared__ float s_inter[4];
  __shared__ float s_mc[2];
  const int bm = blockIdx.x;
  const int tid = threadIdx.x;  // 256 threads
  const float* wb = ws + WS_BASE + (size_t)bm * WS_BM_STRIDE;

  {
    int c = tid;
    float f = 0.f;
#pragma unroll
    for (int pp = 0; pp < NP; ++pp) f += wb[pp * 256 + c];
    s_feat[c] = f * (1.f / NT) + enc_b2[c];
  }
  const float* sc = wb + WS_SC_OFF;
  if (tid < 6) {
    float s = 0.f;
#pragma unroll
    for (int pp = 0; pp < NP; ++pp) s += sc[pp * 8 + tid];
    if (tid == 0) s_hard[0] = -fminf(fmaxf(s * (1.f / NT), 0.f), 15.f) * (1.f / 15.f);
    if (tid == 1) s_hard[1] = fminf(fmaxf(s * (1.f / NT), 0.f), 4.f) * 0.25f;
    if (tid == 2) s_hard[2] = fminf(fmaxf(s * (1.f / NT), 0.f), 6.f) * (1.f / 6.f);
    if (tid == 3) s_hard[3] = fminf(fmaxf(s * (1.f / NT), 0.f), 5.f) * 0.2f;
    if (tid == 4) s_mc[0] = s;
    if (tid == 5) s_mc[1] = s;
  }
  __syncthreads();

  // decoder layer 1: 4 groups x 64 rows of dec_w1, partial sums in LDS
  {
    const int q = tid >> 6, j = tid & 63;
    float a = 0.f;
#pragma unroll 8
    for (int i = 0; i < 64; ++i)
      a += s_feat[q * 64 + i] * dec_w1[(q * 64 + i) * 64 + j];
    s_dhp[q][j] = a;
  }
  __syncthreads();
  if (tid < 64) {
    float acc = dec_b1[tid] + ((s_dhp[0][tid] + s_dhp[1][tid]) +
                               (s_dhp[2][tid] + s_dhp[3][tid]));
    s_dh[tid] = acc > 0.f ? acc : expm1f(acc);  // elu
  }
  __syncthreads();

  if (tid < 4) {
    float acc = dec_b2[tid];
    for (int k = 0; k < 64; ++k) acc += s_dh[k] * dec_w2[k * 4 + tid];
    s_inter[tid] = 1.f / (1.f + __expf(-acc));  // sigmoid
  }
  __syncthreads();

  if (tid == 0) {
    const float* wts = ws + WS_WTS;
    float scv = 0.f;
#pragma unroll
    for (int i = 0; i < 4; ++i) scv += s_hard[i] * wts[i];
#pragma unroll
    for (int i = 0; i < 4; ++i) scv += s_inter[i] * wts[4 + i];
    scv = -scv - 10.f * s_mc[1];
    if (s_mc[0] == 0.f) scv = -INFINITY;
    out_scores[bm] = scv;
  }
}

extern "C" void kernel_launch(void* const* d_in, const int* in_sizes, int n_in,
                              void* d_out, int out_size, void* d_ws, size_t ws_size,
                              hipStream_t stream) {
  const float* ego_traj      = (const float*)d_in[0];
  const float* agents_traj   = (const float*)d_in[2];
  const float* agents_states = (const float*)d_in[3];
  const float* enc_w1 = (const float*)d_in[4];
  const float* enc_b1 = (const float*)d_in[5];
  const float* enc_w2 = (const float*)d_in[6];
  const float* enc_b2 = (const float*)d_in[7];
  const float* dec_w1 = (const float*)d_in[8];
  const float* dec_b1 = (const float*)d_in[9];
  const float* dec_w2 = (const float*)d_in[10];
  const float* dec_b2 = (const float*)d_in[11];
  const float* wd_w1 = (const float*)d_in[12];
  const float* wd_b1 = (const float*)d_in[13];
  const float* wd_w2 = (const float*)d_in[14];
  const float* wd_b2 = (const float*)d_in[15];

  float* out = (float*)d_out;
  float* ws = (float*)d_ws;

  prep_kernel<<<NB + 9, 256, 0, stream>>>(agents_states, enc_w1, enc_b1, enc_w2,
                                          wd_w1, wd_b1, wd_w2, wd_b2, ws, out);
  dim3 grid(NP, NB * NM);
  score_partial<<<grid, 256, 0, stream>>>(
      ego_traj, agents_traj, agents_states, enc_w1, ws);
  combine_kernel<<<NB * NM, 256, 0, stream>>>(
      ws, enc_b2, dec_w1, dec_b1, dec_w2, dec_b2, out);
}